// Round 10
// baseline (333.311 us; speedup 1.0000x reference)
//
#include <hip/hip_runtime.h>
#include <cstdint>

#define BATCH 4
#define CPD 64
#define RES 64
#define NS 131072
#define NF 512
#define FS 2048
#define HID 16

typedef _Float16 __attribute__((ext_vector_type(8))) f16x8;
typedef float __attribute__((ext_vector_type(16))) f32x16;

typedef union { uint4 u; f16x8 v; } Frag;

// ---------------------------------------------------------------------------
// K1: damping + sequential scan (unchanged)
// ---------------------------------------------------------------------------
__global__ __launch_bounds__(256) void k_scan(const float* __restrict__ forces,
                                              const float* __restrict__ dmod,
                                              const float* __restrict__ dparam,
                                              float* __restrict__ damped_t) {
  __shared__ float f_lds[64][129];
  __shared__ float d_lds[64][129];
  const int b = blockIdx.x;
  const int tid = threadIdx.x;
  float dbase = 0.f, carry = 0.f;
  if (tid < 64) {
    float dp = dparam[tid];
    dbase = 0.5f + (0.9999f - 0.5f) / (1.f + expf(-dp));
  }
  for (int ch = 0; ch < 4; ++ch) {
    const int t0 = ch * 128;
    __syncthreads();
    for (int idx = tid; idx < 64 * 128; idx += 256) {
      int c = idx >> 7, tl = idx & 127;
      f_lds[c][tl] = forces[(b * CPD + c) * NF + t0 + tl];
      d_lds[c][tl] = dmod[(b * CPD + c) * NF + t0 + tl];
    }
    __syncthreads();
    if (tid < 64) {
      const int c = tid;
      for (int tl = 0; tl < 128; ++tl) {
        float d = dbase - fabsf(d_lds[c][tl]);
        d = fminf(fmaxf(d, 0.f), 1.f);
        float f = f_lds[c][tl];
        float out = (ch == 0 && tl == 0) ? f : (f + carry) * d;
        carry = out;
        damped_t[(b * NF + t0 + tl) * CPD + c] = out;
      }
    }
  }
}

// ---------------------------------------------------------------------------
// K2: hypernetwork + routing einsum + to_ctrl (unchanged)
// ---------------------------------------------------------------------------
__global__ __launch_bounds__(256) void k_hyper(const float* __restrict__ damped_t,
                                               const float* __restrict__ routing,
                                               const float* __restrict__ W1,
                                               const float* __restrict__ b1,
                                               const float* __restrict__ W2,
                                               const float* __restrict__ b2,
                                               const float* __restrict__ to_control,
                                               float* __restrict__ routed,
                                               float* __restrict__ to_ctrl) {
  __shared__ float xs[4][64];
  __shared__ float hs[4][16];
  __shared__ float rs[4][64];
  const int blk = blockIdx.x;
  const int b = blk >> 7;
  const int t0 = (blk & 127) * 4;
  const int lt = threadIdx.x >> 6;
  const int d = threadIdx.x & 63;
  const int t = t0 + lt;

  xs[lt][d] = damped_t[(b * NF + t) * CPD + d];
  __syncthreads();
  if (d < HID) {
    float a = b1[d];
    for (int c = 0; c < CPD; ++c) a = fmaf(xs[lt][c], W1[c * HID + d], a);
    hs[lt][d] = a > 0.f ? a : 0.2f * a;
  }
  __syncthreads();
  float hreg[HID];
#pragma unroll
  for (int j = 0; j < HID; ++j) hreg[j] = hs[lt][j];

  float acc = 0.f;
  for (int c = 0; c < CPD; ++c) {
    float w = routing[c * RES + d] + b2[c * RES + d];
    const float* w2p = W2 + c * RES + d;
#pragma unroll
    for (int j = 0; j < HID; ++j) w = fmaf(hreg[j], w2p[j * (CPD * RES)], w);
    acc = fmaf(xs[lt][c], w, acc);
  }
  routed[(b * RES + d) * NF + t] = acc;
  rs[lt][d] = acc;
  __syncthreads();
  float tc = 0.f;
  for (int q = 0; q < RES; ++q) tc = fmaf(rs[lt][q], to_control[q * CPD + d], tc);
  to_ctrl[(b * CPD + d) * NF + t] = tc;
}

// ---------------------------------------------------------------------------
// K-zero: zero the atomic boundary strips (every launch -> replay safe)
// ---------------------------------------------------------------------------
__global__ __launch_bounds__(256) void k_zero(float* __restrict__ reso) {
  const int chan = blockIdx.x;
  const size_t base = (size_t)chan * NS;
  for (int i = threadIdx.x; i < 8192; i += 256) {
    int y;
    if (i < 32) y = i;
    else if (i < 32 + 7168) {
      int s = 1 + ((i - 32) >> 10);
      y = 16384 * s - 992 + ((i - 32) & 1023);
    } else {
      y = 130080 + (i - 7200);
    }
    reso[base + y] = 0.f;
  }
}

// ---------------------------------------------------------------------------
// Tiling constants
// ---------------------------------------------------------------------------
#define SPAN 16384
#define ER_GRAN 2312
#define ER_N 18432
#define FC_COPIES 8
#define FC_STRIDE 267
#define FGL_DW (FC_COPIES * FC_STRIDE * 4)   // 8544 dwords per r
#define SMEM_BYTES (ER_GRAN * 16 + FC_COPIES * FC_STRIDE * 16)  // 71168 B
#define GR_CH 16648         // erev granules per channel
#define EN_CHUNKS 9         // 2048-granule chunks per channel (last partial)

// ---------------------------------------------------------------------------
// K-energy (r10): LDS-bounce version — coalesced in, reversed out.
// Block = (chan, chunk): 16384-sample ascending window computed with
// lane-consecutive coalesced noise reads into LDS (f16), then each thread
// emits reversed granules with coalesced 16B stores. Output layout identical
// to r9: erev[chan][y8] ushort k = f16(e[131128 - 8*y8 - k] * 1024).
// ---------------------------------------------------------------------------
__global__ __launch_bounds__(256) void k_energy(const float* __restrict__ routed,
                                                const float* __restrict__ noise,
                                                uint4* __restrict__ erev) {
  __shared__ unsigned short els[16384];   // 32 KB
  const int chunk = blockIdx.x % EN_CHUNKS;
  const int chan = blockIdx.x / EN_CHUNKS;
  const float* rp = routed + chan * NF;
  const float* np = noise + (size_t)chan * NS;
  const int nhi = 131128 - 16384 * chunk;   // multiple of 8
  const int nlo = nhi - 16383;

  // phase 1: ascending, coalesced
  for (int j = threadIdx.x; j < 16384; j += 256) {
    int n = nlo + j;
    float e = 0.f;
    if (n >= 0 && n < NS) {
      float pos = ((float)n + 0.5f) * (1.f / 256.f) - 0.5f;
      pos = fminf(fmaxf(pos, 0.f), 511.f);
      float fi = floorf(pos);
      int i0 = (int)fi;
      int i1 = min(i0 + 1, 511);
      float fr = pos - fi;
      float u = rp[i0] * (1.f - fr) + rp[i1] * fr;
      e = u * np[n];
    }
    union { _Float16 h; unsigned short s; } cv;
    cv.h = (_Float16)(e * 1024.f);
    els[j] = cv.s;
  }
  __syncthreads();

  // phase 2: reversed granules, coalesced stores
  const int lim = min(2048, GR_CH - 2048 * chunk);
  for (int g = threadIdx.x; g < lim; g += 256) {
    const uint4 din = *(const uint4*)((const unsigned char*)els + (32752 - 16 * g));
    uint4 dout;
    dout.x = (din.w >> 16) | (din.w << 16);
    dout.y = (din.z >> 16) | (din.z << 16);
    dout.z = (din.y >> 16) | (din.y << 16);
    dout.w = (din.x >> 16) | (din.x << 16);
    erev[(size_t)chan * GR_CH + 2048 * chunk + g] = dout;
  }
}

// ---------------------------------------------------------------------------
// K-filter: per-r 8-shift f16 tap-pair table (unchanged)
// ---------------------------------------------------------------------------
__global__ __launch_bounds__(256) void k_filter(const float* __restrict__ filters,
                                                unsigned* __restrict__ fgl) {
  const int r = blockIdx.x;
  const float* fr = filters + r * FS;
  unsigned* dst = fgl + r * FGL_DW;
  for (int idx = threadIdx.x; idx < FGL_DW; idx += 256) {
    int c = idx / (FC_STRIDE * 4);
    int d = idx - c * (FC_STRIDE * 4);
    int t0 = 2 * d + c - 32;
    float f0 = (t0 >= 0 && t0 < FS) ? fr[t0] : 0.f;
    float f1 = (t0 + 1 >= 0 && t0 + 1 < FS) ? fr[t0 + 1] : 0.f;
    union { _Float16 h[2]; unsigned u; } P;
    P.h[0] = (_Float16)f0;
    P.h[1] = (_Float16)f1;
    dst[idx] = P.u;
  }
}

// ---------------------------------------------------------------------------
// K3: block-Hankel GEMM conv (unchanged from r9)
// ---------------------------------------------------------------------------
__global__ __launch_bounds__(512, 4) void k_conv(const float* __restrict__ routed,
                                                 const float* __restrict__ noise,
                                                 const float* __restrict__ filters,
                                                 float* __restrict__ outp,
                                                 const uint4* __restrict__ erev,
                                                 const unsigned* __restrict__ fgl,
                                                 int use_pre) {
  __shared__ __align__(16) unsigned char smem[SMEM_BYTES];
  unsigned char* erb = smem;
  unsigned char* fcb = smem + ER_GRAN * 16;

  const int tid = threadIdx.x;
  const int seg = blockIdx.x & 7;
  const int r = (blockIdx.x >> 3) & 63;
  const int b = blockIdx.x >> 9;
  const int NB = seg * SPAN;
  const int E0 = NB + SPAN + 32;
  const int chan = b * RES + r;

  if (use_pre) {
    const int o8 = 16387 - (seg + 1) * 2048;
    const uint4* ef = erev + (size_t)chan * GR_CH + o8;
    uint4* er4 = (uint4*)erb;
    for (int s = tid; s < 2304; s += 512) er4[s] = ef[s ^ ((s >> 3) & 7)];
    const uint4* fg = (const uint4*)(fgl + r * FGL_DW);
    uint4* fc4 = (uint4*)fcb;
    for (int q = tid; q < FGL_DW / 4; q += 512) fc4[q] = fg[q];
  } else {
    const float* rp = routed + chan * NF;
    const float* npz = noise + (size_t)chan * NS;
    unsigned* f32p = (unsigned*)fcb;
    const float* fr = filters + r * FS;
    for (int idx = tid; idx < FGL_DW; idx += 512) {
      int c = idx / (FC_STRIDE * 4);
      int d = idx - c * (FC_STRIDE * 4);
      int t0 = 2 * d + c - 32;
      float f0 = (t0 >= 0 && t0 < FS) ? fr[t0] : 0.f;
      float f1 = (t0 + 1 >= 0 && t0 + 1 < FS) ? fr[t0 + 1] : 0.f;
      union { _Float16 h[2]; unsigned u; } P;
      P.h[0] = (_Float16)f0;
      P.h[1] = (_Float16)f1;
      f32p[idx] = P.u;
    }
    unsigned* er32 = (unsigned*)erb;
    for (int x2 = tid; x2 < ER_N / 2; x2 += 512) {
      int x = 2 * x2;
      union { _Float16 h[2]; unsigned u; } P;
#pragma unroll
      for (int k = 0; k < 2; ++k) {
        int n = E0 - x - k;
        float e = 0.f;
        if (n >= 0 && n < NS) {
          float pos = ((float)n + 0.5f) * (1.f / 256.f) - 0.5f;
          pos = fminf(fmaxf(pos, 0.f), 511.f);
          float fi = floorf(pos);
          int i0 = (int)fi;
          int i1 = min(i0 + 1, 511);
          float fr2 = pos - fi;
          float u = rp[i0] * (1.f - fr2) + rp[i1] * fr2;
          e = u * npz[n];
        }
        P.h[k] = (_Float16)(e * 1024.f);
      }
      int g = x >> 3;
      int sig = g ^ ((g >> 3) & 7);
      er32[sig * 4 + ((x & 7) >> 1)] = P.u;
    }
  }
  __syncthreads();

  const int w = tid >> 6;
  const int l = tid & 63;
  const int row = l & 31;
  const int h = l >> 5;

  const int gaA = 2048 - 256 * w + 4 * row + h;
  const int gaB = gaA - 128;
  const int qcb = (row & 7) * FC_STRIDE + (row >> 3) + h;

  f32x16 p00, p01, p10, p11;
#pragma unroll
  for (int i = 0; i < 16; ++i) { p00[i] = 0.f; p01[i] = 0.f; p10[i] = 0.f; p11[i] = 0.f; }

#define LOADA(DST, GB, SG_)                                                   \
  { int g = (GB) + 2 * (SG_); int ab = (g ^ ((g >> 3) & 7)) << 4;             \
    DST.u = *(const uint4*)(erb + ab); }
#define LOADBF(DST, SG_, J_)                                                  \
  { int gb = qcb + 2 * (SG_) + 128 * (J_);                                    \
    DST.u = *(const uint4*)(fcb + (gb << 4)); }

  for (int sg = 0; sg < 2; ++sg) {
    Frag B0, A0, A1;
    LOADBF(B0, sg, 0)
    LOADA(A0, gaA, sg) LOADA(A1, gaB, sg)
    p00 = __builtin_amdgcn_mfma_f32_32x32x16_f16(A0.v, B0.v, p00, 0, 0, 0);
    p10 = __builtin_amdgcn_mfma_f32_32x32x16_f16(A1.v, B0.v, p10, 0, 0, 0);
  }
  for (int sg = 2; sg < 66; ++sg) {
    Frag B0, B1, A0, A1;
    LOADBF(B0, sg, 0) LOADBF(B1, sg, 1)
    LOADA(A0, gaA, sg) LOADA(A1, gaB, sg)
    p00 = __builtin_amdgcn_mfma_f32_32x32x16_f16(A0.v, B0.v, p00, 0, 0, 0);
    p01 = __builtin_amdgcn_mfma_f32_32x32x16_f16(A0.v, B1.v, p01, 0, 0, 0);
    p10 = __builtin_amdgcn_mfma_f32_32x32x16_f16(A1.v, B0.v, p10, 0, 0, 0);
    p11 = __builtin_amdgcn_mfma_f32_32x32x16_f16(A1.v, B1.v, p11, 0, 0, 0);
  }

  if (seg == 7 && w == 7) {
    f32x16 ax;
#pragma unroll
    for (int i = 0; i < 16; ++i) ax[i] = 0.f;
    const int ge = 4 * row + h;
    for (int sg = 0; sg < 66; ++sg) {
      Frag Bx, Ax;
      LOADBF(Bx, sg, 0)
      LOADA(Ax, ge, sg)
      ax = __builtin_amdgcn_mfma_f32_32x32x16_f16(Ax.v, Bx.v, ax, 0, 0, 0);
    }
#pragma unroll
    for (int i = 0; i < 16; ++i) p11[i] += ax[i];
  }
#undef LOADA
#undef LOADBF

  float* cbase = outp + (size_t)chan * NS;
  const float scale = 1.f / 1024.f;

  {
    float* po = cbase + NB + 1024 * (2 * w + 1);
#pragma unroll
    for (int rg = 0; rg < 16; ++rg) {
      int crow = (rg & 3) + 8 * (rg >> 2) + 4 * h;
      po[row - 32 * crow] = (p10[rg] + p01[rg]) * scale;
    }
  }

  __syncthreads();
  float* scr = (float*)smem;
#pragma unroll
  for (int rg = 0; rg < 16; ++rg) scr[w * 1024 + rg * 64 + l] = p11[rg];
  __syncthreads();

  if (w >= 1) {
    float* po = cbase + NB + 1024 * (2 * w);
#pragma unroll
    for (int rg = 0; rg < 16; ++rg) {
      int crow = (rg & 3) + 8 * (rg >> 2) + 4 * h;
      po[row - 32 * crow] = (p00[rg] + scr[(w - 1) * 1024 + rg * 64 + l]) * scale;
    }
  } else {
#pragma unroll
    for (int rg = 0; rg < 16; ++rg) {
      int crow = (rg & 3) + 8 * (rg >> 2) + 4 * h;
      int y = NB + row - 32 * crow;
      if (y >= 0) atomicAdd(cbase + y, p00[rg] * scale);
    }
  }
  if (w == 7) {
#pragma unroll
    for (int rg = 0; rg < 16; ++rg) {
      int crow = (rg & 3) + 8 * (rg >> 2) + 4 * h;
      int y = NB + SPAN + row - 32 * crow;
      if (y < NS) atomicAdd(cbase + y, p11[rg] * scale);
    }
  }
}

// ---------------------------------------------------------------------------
extern "C" void kernel_launch(void* const* d_in, const int* in_sizes, int n_in,
                              void* d_out, int out_size, void* d_ws, size_t ws_size,
                              hipStream_t stream) {
  const float* forces     = (const float*)d_in[0];
  const float* dmod       = (const float*)d_in[1];
  const float* noise      = (const float*)d_in[2];
  const float* dparam     = (const float*)d_in[3];
  const float* routing    = (const float*)d_in[4];
  const float* W1         = (const float*)d_in[5];
  const float* b1         = (const float*)d_in[6];
  const float* W2         = (const float*)d_in[7];
  const float* b2         = (const float*)d_in[8];
  const float* filters    = (const float*)d_in[9];
  const float* to_control = (const float*)d_in[10];

  float* out = (float*)d_out;
  float* to_ctrl = out;                                  // (B,CPD,NF)
  float* reso = out + BATCH * CPD * NF;                  // (B,RES,NS)

  char* ws = (char*)d_ws;
  float* damped_t = (float*)ws;                          // 512 KB
  float* routed = (float*)(ws + (512 << 10));            // 512 KB
  unsigned* fgl = (unsigned*)(ws + (1 << 20));           // 2.19 MB
  uint4* erev = (uint4*)(ws + (4 << 20));                // 68.2 MB
  const size_t need = (size_t)(4 << 20) + (size_t)256 * GR_CH * 16;
  const int use_pre = (ws_size >= need) ? 1 : 0;

  k_scan<<<BATCH, 256, 0, stream>>>(forces, dmod, dparam, damped_t);
  k_hyper<<<BATCH * NF / 4, 256, 0, stream>>>(damped_t, routing, W1, b1, W2, b2,
                                              to_control, routed, to_ctrl);
  if (use_pre) {
    k_filter<<<RES, 256, 0, stream>>>(filters, fgl);
    k_energy<<<BATCH * RES * EN_CHUNKS, 256, 0, stream>>>(routed, noise, erev);
  }
  k_zero<<<BATCH * RES, 256, 0, stream>>>(reso);
  k_conv<<<BATCH * RES * (NS / SPAN), 512, 0, stream>>>(routed, noise, filters,
                                                        reso, erev, fgl, use_pre);
}

// Round 11
// 254.225 us; speedup vs baseline: 1.3111x; 1.3111x over previous
//
#include <hip/hip_runtime.h>
#include <cstdint>

#define BATCH 4
#define CPD 64
#define RES 64
#define NS 131072
#define NF 512
#define FS 2048
#define HID 16

typedef _Float16 __attribute__((ext_vector_type(8))) f16x8;
typedef float __attribute__((ext_vector_type(16))) f32x16;

typedef union { uint4 u; f16x8 v; } Frag;

// ---------------------------------------------------------------------------
// K1: damping + sequential scan (unchanged)
// ---------------------------------------------------------------------------
__global__ __launch_bounds__(256) void k_scan(const float* __restrict__ forces,
                                              const float* __restrict__ dmod,
                                              const float* __restrict__ dparam,
                                              float* __restrict__ damped_t) {
  __shared__ float f_lds[64][129];
  __shared__ float d_lds[64][129];
  const int b = blockIdx.x;
  const int tid = threadIdx.x;
  float dbase = 0.f, carry = 0.f;
  if (tid < 64) {
    float dp = dparam[tid];
    dbase = 0.5f + (0.9999f - 0.5f) / (1.f + expf(-dp));
  }
  for (int ch = 0; ch < 4; ++ch) {
    const int t0 = ch * 128;
    __syncthreads();
    for (int idx = tid; idx < 64 * 128; idx += 256) {
      int c = idx >> 7, tl = idx & 127;
      f_lds[c][tl] = forces[(b * CPD + c) * NF + t0 + tl];
      d_lds[c][tl] = dmod[(b * CPD + c) * NF + t0 + tl];
    }
    __syncthreads();
    if (tid < 64) {
      const int c = tid;
      for (int tl = 0; tl < 128; ++tl) {
        float d = dbase - fabsf(d_lds[c][tl]);
        d = fminf(fmaxf(d, 0.f), 1.f);
        float f = f_lds[c][tl];
        float out = (ch == 0 && tl == 0) ? f : (f + carry) * d;
        carry = out;
        damped_t[(b * NF + t0 + tl) * CPD + c] = out;
      }
    }
  }
}

// ---------------------------------------------------------------------------
// K2: hypernetwork + routing einsum + to_ctrl (unchanged)
// ---------------------------------------------------------------------------
__global__ __launch_bounds__(256) void k_hyper(const float* __restrict__ damped_t,
                                               const float* __restrict__ routing,
                                               const float* __restrict__ W1,
                                               const float* __restrict__ b1,
                                               const float* __restrict__ W2,
                                               const float* __restrict__ b2,
                                               const float* __restrict__ to_control,
                                               float* __restrict__ routed,
                                               float* __restrict__ to_ctrl) {
  __shared__ float xs[4][64];
  __shared__ float hs[4][16];
  __shared__ float rs[4][64];
  const int blk = blockIdx.x;
  const int b = blk >> 7;
  const int t0 = (blk & 127) * 4;
  const int lt = threadIdx.x >> 6;
  const int d = threadIdx.x & 63;
  const int t = t0 + lt;

  xs[lt][d] = damped_t[(b * NF + t) * CPD + d];
  __syncthreads();
  if (d < HID) {
    float a = b1[d];
    for (int c = 0; c < CPD; ++c) a = fmaf(xs[lt][c], W1[c * HID + d], a);
    hs[lt][d] = a > 0.f ? a : 0.2f * a;
  }
  __syncthreads();
  float hreg[HID];
#pragma unroll
  for (int j = 0; j < HID; ++j) hreg[j] = hs[lt][j];

  float acc = 0.f;
  for (int c = 0; c < CPD; ++c) {
    float w = routing[c * RES + d] + b2[c * RES + d];
    const float* w2p = W2 + c * RES + d;
#pragma unroll
    for (int j = 0; j < HID; ++j) w = fmaf(hreg[j], w2p[j * (CPD * RES)], w);
    acc = fmaf(xs[lt][c], w, acc);
  }
  routed[(b * RES + d) * NF + t] = acc;
  rs[lt][d] = acc;
  __syncthreads();
  float tc = 0.f;
  for (int q = 0; q < RES; ++q) tc = fmaf(rs[lt][q], to_control[q * CPD + d], tc);
  to_ctrl[(b * CPD + d) * NF + t] = tc;
}

// ---------------------------------------------------------------------------
// K-zero: zero the atomic boundary strips (every launch -> replay safe)
// ---------------------------------------------------------------------------
__global__ __launch_bounds__(256) void k_zero(float* __restrict__ reso) {
  const int chan = blockIdx.x;
  const size_t base = (size_t)chan * NS;
  for (int i = threadIdx.x; i < 8192; i += 256) {
    int y;
    if (i < 32) y = i;
    else if (i < 32 + 7168) {
      int s = 1 + ((i - 32) >> 10);
      y = 16384 * s - 992 + ((i - 32) & 1023);
    } else {
      y = 130080 + (i - 7200);
    }
    reso[base + y] = 0.f;
  }
}

// ---------------------------------------------------------------------------
// Tiling constants
// ---------------------------------------------------------------------------
#define SPAN 16384
#define ER_GRAN 2312
#define ER_N 18432
#define FC_COPIES 8
#define FC_STRIDE 267
#define FGL_DW (FC_COPIES * FC_STRIDE * 4)   // 8544 dwords per r
#define SMEM_BYTES (ER_GRAN * 16 + FC_COPIES * FC_STRIDE * 16)  // 71168 B

// ---------------------------------------------------------------------------
// K-filter: per-r 8-shift f16 tap-pair table (unchanged)
// ---------------------------------------------------------------------------
__global__ __launch_bounds__(256) void k_filter(const float* __restrict__ filters,
                                                unsigned* __restrict__ fgl) {
  const int r = blockIdx.x;
  const float* fr = filters + r * FS;
  unsigned* dst = fgl + r * FGL_DW;
  for (int idx = threadIdx.x; idx < FGL_DW; idx += 256) {
    int c = idx / (FC_STRIDE * 4);
    int d = idx - c * (FC_STRIDE * 4);
    int t0 = 2 * d + c - 32;
    float f0 = (t0 >= 0 && t0 < FS) ? fr[t0] : 0.f;
    float f1 = (t0 + 1 >= 0 && t0 + 1 < FS) ? fr[t0 + 1] : 0.f;
    union { _Float16 h[2]; unsigned u; } P;
    P.h[0] = (_Float16)f0;
    P.h[1] = (_Float16)f1;
    dst[idx] = P.u;
  }
}

// ---------------------------------------------------------------------------
// K3: block-Hankel GEMM conv, r11: fused FAST energy staging.
// Staging A (energy): per 8-sample granule, ascending coalesced float4 noise
// loads (lane t <-> granule 2303-t), incremental single-span interpolation
// (i0 = ((n+128)>>8)-1 constant within granule; u*1024*noise via 2 table
// loads + 16 FMA), reversed in-register pack, swizzled ds_write_b128.
// Edge/boundary granules (1/32 + block edges) use the exact per-sample path.
// Staging B (filter): copy from precomputed fgl table (L2-resident).
// Compute loop / epilogue: unchanged from r9 (147 us proven).
// ---------------------------------------------------------------------------
__global__ __launch_bounds__(512, 4) void k_conv(const float* __restrict__ routed,
                                                 const float* __restrict__ noise,
                                                 float* __restrict__ outp,
                                                 const unsigned* __restrict__ fgl) {
  __shared__ __align__(16) unsigned char smem[SMEM_BYTES];
  unsigned char* erb = smem;
  unsigned char* fcb = smem + ER_GRAN * 16;

  const int tid = threadIdx.x;
  const int seg = blockIdx.x & 7;
  const int r = (blockIdx.x >> 3) & 63;
  const int b = blockIdx.x >> 9;
  const int NB = seg * SPAN;
  const int E0 = NB + SPAN + 32;      // er[x] = e[E0-x]*1024
  const int chan = b * RES + r;

  // ---- staging B: filter table copy ----
  {
    const uint4* fg = (const uint4*)(fgl + r * FGL_DW);
    uint4* fc4 = (uint4*)fcb;
    for (int q = tid; q < FGL_DW / 4; q += 512) fc4[q] = fg[q];
  }

  // ---- staging A: fused energy ----
  {
    const float* rp = routed + chan * NF;
    const float* npz = noise + (size_t)chan * NS;
    const int n0base = E0 - 18431;
    for (int t = tid; t < 2304; t += 512) {
      const int n0 = n0base + 8 * t;     // ascending with lane -> coalesced
      const int g = 2303 - t;            // target granule (descending)
      float ev[8];
      const int q0 = n0 + 128;
      const int rem = q0 & 255;
      if (n0 >= 128 && rem <= 248 && n0 + 7 < NS) {
        // fast path: whole granule in one interp span
        const int i0 = (q0 >> 8) - 1;
        const int i1 = min(i0 + 1, 511);
        const float c0 = rp[i0];
        const float S = 4.f * (rp[i1] - c0);      // 1024 * (c1-c0) / 256
        const float C0 = 1024.f * c0;
        const float4 na = *(const float4*)(npz + n0);
        const float4 nb = *(const float4*)(npz + n0 + 4);
        const float r5 = (float)rem + 0.5f;
        ev[0] = fmaf(S, r5 + 0.f, C0) * na.x;
        ev[1] = fmaf(S, r5 + 1.f, C0) * na.y;
        ev[2] = fmaf(S, r5 + 2.f, C0) * na.z;
        ev[3] = fmaf(S, r5 + 3.f, C0) * na.w;
        ev[4] = fmaf(S, r5 + 4.f, C0) * nb.x;
        ev[5] = fmaf(S, r5 + 5.f, C0) * nb.y;
        ev[6] = fmaf(S, r5 + 6.f, C0) * nb.z;
        ev[7] = fmaf(S, r5 + 7.f, C0) * nb.w;
      } else {
        // slow path: exact per-sample (edges, span crossings)
#pragma unroll
        for (int k = 0; k < 8; ++k) {
          int n = n0 + k;
          float e = 0.f;
          if (n >= 0 && n < NS) {
            float pos = ((float)n + 0.5f) * (1.f / 256.f) - 0.5f;
            pos = fminf(fmaxf(pos, 0.f), 511.f);
            float fi = floorf(pos);
            int i0 = (int)fi;
            int i1 = min(i0 + 1, 511);
            float fr = pos - fi;
            float u = rp[i0] * (1.f - fr) + rp[i1] * fr;
            e = u * npz[n] * 1024.f;
          }
          ev[k] = e;
        }
      }
      union { _Float16 h[8]; uint4 u; } O;   // reversed pack
      O.h[0] = (_Float16)ev[7]; O.h[1] = (_Float16)ev[6];
      O.h[2] = (_Float16)ev[5]; O.h[3] = (_Float16)ev[4];
      O.h[4] = (_Float16)ev[3]; O.h[5] = (_Float16)ev[2];
      O.h[6] = (_Float16)ev[1]; O.h[7] = (_Float16)ev[0];
      const int gs = g ^ ((g >> 3) & 7);
      *(uint4*)(erb + (gs << 4)) = O.u;
    }
  }
  __syncthreads();

  const int w = tid >> 6;
  const int l = tid & 63;
  const int row = l & 31;
  const int h = l >> 5;

  const int gaA = 2048 - 256 * w + 4 * row + h;
  const int gaB = gaA - 128;
  const int qcb = (row & 7) * FC_STRIDE + (row >> 3) + h;

  f32x16 p00, p01, p10, p11;
#pragma unroll
  for (int i = 0; i < 16; ++i) { p00[i] = 0.f; p01[i] = 0.f; p10[i] = 0.f; p11[i] = 0.f; }

#define LOADA(DST, GB, SG_)                                                   \
  { int g = (GB) + 2 * (SG_); int ab = (g ^ ((g >> 3) & 7)) << 4;             \
    DST.u = *(const uint4*)(erb + ab); }
#define LOADBF(DST, SG_, J_)                                                  \
  { int gb = qcb + 2 * (SG_) + 128 * (J_);                                    \
    DST.u = *(const uint4*)(fcb + (gb << 4)); }

  for (int sg = 0; sg < 2; ++sg) {
    Frag B0, A0, A1;
    LOADBF(B0, sg, 0)
    LOADA(A0, gaA, sg) LOADA(A1, gaB, sg)
    p00 = __builtin_amdgcn_mfma_f32_32x32x16_f16(A0.v, B0.v, p00, 0, 0, 0);
    p10 = __builtin_amdgcn_mfma_f32_32x32x16_f16(A1.v, B0.v, p10, 0, 0, 0);
  }
  for (int sg = 2; sg < 66; ++sg) {
    Frag B0, B1, A0, A1;
    LOADBF(B0, sg, 0) LOADBF(B1, sg, 1)
    LOADA(A0, gaA, sg) LOADA(A1, gaB, sg)
    p00 = __builtin_amdgcn_mfma_f32_32x32x16_f16(A0.v, B0.v, p00, 0, 0, 0);
    p01 = __builtin_amdgcn_mfma_f32_32x32x16_f16(A0.v, B1.v, p01, 0, 0, 0);
    p10 = __builtin_amdgcn_mfma_f32_32x32x16_f16(A1.v, B0.v, p10, 0, 0, 0);
    p11 = __builtin_amdgcn_mfma_f32_32x32x16_f16(A1.v, B1.v, p11, 0, 0, 0);
  }

  if (seg == 7 && w == 7) {           // global-top orphan phase-0 half
    f32x16 ax;
#pragma unroll
    for (int i = 0; i < 16; ++i) ax[i] = 0.f;
    const int ge = 4 * row + h;
    for (int sg = 0; sg < 66; ++sg) {
      Frag Bx, Ax;
      LOADBF(Bx, sg, 0)
      LOADA(Ax, ge, sg)
      ax = __builtin_amdgcn_mfma_f32_32x32x16_f16(Ax.v, Bx.v, ax, 0, 0, 0);
    }
#pragma unroll
    for (int i = 0; i < 16; ++i) p11[i] += ax[i];
  }
#undef LOADA
#undef LOADBF

  float* cbase = outp + (size_t)chan * NS;
  const float scale = 1.f / 1024.f;

  {
    float* po = cbase + NB + 1024 * (2 * w + 1);
#pragma unroll
    for (int rg = 0; rg < 16; ++rg) {
      int crow = (rg & 3) + 8 * (rg >> 2) + 4 * h;
      po[row - 32 * crow] = (p10[rg] + p01[rg]) * scale;
    }
  }

  __syncthreads();
  float* scr = (float*)smem;
#pragma unroll
  for (int rg = 0; rg < 16; ++rg) scr[w * 1024 + rg * 64 + l] = p11[rg];
  __syncthreads();

  if (w >= 1) {
    float* po = cbase + NB + 1024 * (2 * w);
#pragma unroll
    for (int rg = 0; rg < 16; ++rg) {
      int crow = (rg & 3) + 8 * (rg >> 2) + 4 * h;
      po[row - 32 * crow] = (p00[rg] + scr[(w - 1) * 1024 + rg * 64 + l]) * scale;
    }
  } else {
#pragma unroll
    for (int rg = 0; rg < 16; ++rg) {
      int crow = (rg & 3) + 8 * (rg >> 2) + 4 * h;
      int y = NB + row - 32 * crow;
      if (y >= 0) atomicAdd(cbase + y, p00[rg] * scale);
    }
  }
  if (w == 7) {
#pragma unroll
    for (int rg = 0; rg < 16; ++rg) {
      int crow = (rg & 3) + 8 * (rg >> 2) + 4 * h;
      int y = NB + SPAN + row - 32 * crow;
      if (y < NS) atomicAdd(cbase + y, p11[rg] * scale);
    }
  }
}

// ---------------------------------------------------------------------------
extern "C" void kernel_launch(void* const* d_in, const int* in_sizes, int n_in,
                              void* d_out, int out_size, void* d_ws, size_t ws_size,
                              hipStream_t stream) {
  const float* forces     = (const float*)d_in[0];
  const float* dmod       = (const float*)d_in[1];
  const float* noise      = (const float*)d_in[2];
  const float* dparam     = (const float*)d_in[3];
  const float* routing    = (const float*)d_in[4];
  const float* W1         = (const float*)d_in[5];
  const float* b1         = (const float*)d_in[6];
  const float* W2         = (const float*)d_in[7];
  const float* b2         = (const float*)d_in[8];
  const float* filters    = (const float*)d_in[9];
  const float* to_control = (const float*)d_in[10];

  float* out = (float*)d_out;
  float* to_ctrl = out;                                  // (B,CPD,NF)
  float* reso = out + BATCH * CPD * NF;                  // (B,RES,NS)

  char* ws = (char*)d_ws;
  float* damped_t = (float*)ws;                          // 512 KB
  float* routed = (float*)(ws + (512 << 10));            // 512 KB
  unsigned* fgl = (unsigned*)(ws + (1 << 20));           // 2.19 MB

  k_scan<<<BATCH, 256, 0, stream>>>(forces, dmod, dparam, damped_t);
  k_hyper<<<BATCH * NF / 4, 256, 0, stream>>>(damped_t, routing, W1, b1, W2, b2,
                                              to_control, routed, to_ctrl);
  k_filter<<<RES, 256, 0, stream>>>(filters, fgl);
  k_zero<<<BATCH * RES, 256, 0, stream>>>(reso);
  k_conv<<<BATCH * RES * (NS / SPAN), 512, 0, stream>>>(routed, noise, reso, fgl);
}

// Round 12
// 224.080 us; speedup vs baseline: 1.4875x; 1.1345x over previous
//
#include <hip/hip_runtime.h>
#include <cstdint>

#define BATCH 4
#define CPD 64
#define RES 64
#define NS 131072
#define NF 512
#define FS 2048
#define HID 16

typedef _Float16 __attribute__((ext_vector_type(8))) f16x8;
typedef float __attribute__((ext_vector_type(16))) f32x16;

typedef union { uint4 u; f16x8 v; } Frag;

// ---------------------------------------------------------------------------
// K1: damping + sequential scan (unchanged)
// ---------------------------------------------------------------------------
__global__ __launch_bounds__(256) void k_scan(const float* __restrict__ forces,
                                              const float* __restrict__ dmod,
                                              const float* __restrict__ dparam,
                                              float* __restrict__ damped_t) {
  __shared__ float f_lds[64][129];
  __shared__ float d_lds[64][129];
  const int b = blockIdx.x;
  const int tid = threadIdx.x;
  float dbase = 0.f, carry = 0.f;
  if (tid < 64) {
    float dp = dparam[tid];
    dbase = 0.5f + (0.9999f - 0.5f) / (1.f + expf(-dp));
  }
  for (int ch = 0; ch < 4; ++ch) {
    const int t0 = ch * 128;
    __syncthreads();
    for (int idx = tid; idx < 64 * 128; idx += 256) {
      int c = idx >> 7, tl = idx & 127;
      f_lds[c][tl] = forces[(b * CPD + c) * NF + t0 + tl];
      d_lds[c][tl] = dmod[(b * CPD + c) * NF + t0 + tl];
    }
    __syncthreads();
    if (tid < 64) {
      const int c = tid;
      for (int tl = 0; tl < 128; ++tl) {
        float d = dbase - fabsf(d_lds[c][tl]);
        d = fminf(fmaxf(d, 0.f), 1.f);
        float f = f_lds[c][tl];
        float out = (ch == 0 && tl == 0) ? f : (f + carry) * d;
        carry = out;
        damped_t[(b * NF + t0 + tl) * CPD + c] = out;
      }
    }
  }
}

// ---------------------------------------------------------------------------
// K2: hypernetwork + routing einsum + to_ctrl (unchanged)
// ---------------------------------------------------------------------------
__global__ __launch_bounds__(256) void k_hyper(const float* __restrict__ damped_t,
                                               const float* __restrict__ routing,
                                               const float* __restrict__ W1,
                                               const float* __restrict__ b1,
                                               const float* __restrict__ W2,
                                               const float* __restrict__ b2,
                                               const float* __restrict__ to_control,
                                               float* __restrict__ routed,
                                               float* __restrict__ to_ctrl) {
  __shared__ float xs[4][64];
  __shared__ float hs[4][16];
  __shared__ float rs[4][64];
  const int blk = blockIdx.x;
  const int b = blk >> 7;
  const int t0 = (blk & 127) * 4;
  const int lt = threadIdx.x >> 6;
  const int d = threadIdx.x & 63;
  const int t = t0 + lt;

  xs[lt][d] = damped_t[(b * NF + t) * CPD + d];
  __syncthreads();
  if (d < HID) {
    float a = b1[d];
    for (int c = 0; c < CPD; ++c) a = fmaf(xs[lt][c], W1[c * HID + d], a);
    hs[lt][d] = a > 0.f ? a : 0.2f * a;
  }
  __syncthreads();
  float hreg[HID];
#pragma unroll
  for (int j = 0; j < HID; ++j) hreg[j] = hs[lt][j];

  float acc = 0.f;
  for (int c = 0; c < CPD; ++c) {
    float w = routing[c * RES + d] + b2[c * RES + d];
    const float* w2p = W2 + c * RES + d;
#pragma unroll
    for (int j = 0; j < HID; ++j) w = fmaf(hreg[j], w2p[j * (CPD * RES)], w);
    acc = fmaf(xs[lt][c], w, acc);
  }
  routed[(b * RES + d) * NF + t] = acc;
  rs[lt][d] = acc;
  __syncthreads();
  float tc = 0.f;
  for (int q = 0; q < RES; ++q) tc = fmaf(rs[lt][q], to_control[q * CPD + d], tc);
  to_ctrl[(b * CPD + d) * NF + t] = tc;
}

// ---------------------------------------------------------------------------
// K-zero: zero the atomic boundary strips (every launch -> replay safe)
// ---------------------------------------------------------------------------
__global__ __launch_bounds__(256) void k_zero(float* __restrict__ reso) {
  const int chan = blockIdx.x;
  const size_t base = (size_t)chan * NS;
  for (int i = threadIdx.x; i < 8192; i += 256) {
    int y;
    if (i < 32) y = i;
    else if (i < 32 + 7168) {
      int s = 1 + ((i - 32) >> 10);
      y = 16384 * s - 992 + ((i - 32) & 1023);
    } else {
      y = 130080 + (i - 7200);
    }
    reso[base + y] = 0.f;
  }
}

// ---------------------------------------------------------------------------
// Tiling constants
// ---------------------------------------------------------------------------
#define SPAN 16384
#define ER_GRAN 2312
#define FC_COPIES 8
#define FC_STRIDE 267
#define FGL_DW (FC_COPIES * FC_STRIDE * 4)   // 8544 dwords per r
#define SMEM_BYTES (ER_GRAN * 16 + FC_COPIES * FC_STRIDE * 16)  // 71168 B

// ---------------------------------------------------------------------------
// K-filter: per-r 8-shift f16 tap-pair table (unchanged)
// ---------------------------------------------------------------------------
__global__ __launch_bounds__(256) void k_filter(const float* __restrict__ filters,
                                                unsigned* __restrict__ fgl) {
  const int r = blockIdx.x;
  const float* fr = filters + r * FS;
  unsigned* dst = fgl + r * FGL_DW;
  for (int idx = threadIdx.x; idx < FGL_DW; idx += 256) {
    int c = idx / (FC_STRIDE * 4);
    int d = idx - c * (FC_STRIDE * 4);
    int t0 = 2 * d + c - 32;
    float f0 = (t0 >= 0 && t0 < FS) ? fr[t0] : 0.f;
    float f1 = (t0 + 1 >= 0 && t0 + 1 < FS) ? fr[t0 + 1] : 0.f;
    union { _Float16 h[2]; unsigned u; } P;
    P.h[0] = (_Float16)f0;
    P.h[1] = (_Float16)f1;
    dst[idx] = P.u;
  }
}

// ---------------------------------------------------------------------------
// K3: block-Hankel GEMM conv, r12: branchless + statically-unrolled staging.
// Per granule: 2 clamped float4 noise loads + 4 rp gathers (span pair for
// pos0 and pos7; per-sample cndmask select), exact-clamped interp via
// i0 = min(floor(pos),510), frac in [0,1]. No divergent slow path. Unrolled
// 4x + wave-uniform tail so the scheduler hoists all staging loads.
// Compute loop / epilogue: unchanged (147 us proven with copy staging).
// ---------------------------------------------------------------------------
__global__ __launch_bounds__(512, 4) void k_conv(const float* __restrict__ routed,
                                                 const float* __restrict__ noise,
                                                 float* __restrict__ outp,
                                                 const unsigned* __restrict__ fgl) {
  __shared__ __align__(16) unsigned char smem[SMEM_BYTES];
  unsigned char* erb = smem;
  unsigned char* fcb = smem + ER_GRAN * 16;

  const int tid = threadIdx.x;
  const int seg = blockIdx.x & 7;
  const int r = (blockIdx.x >> 3) & 63;
  const int b = blockIdx.x >> 9;
  const int NB = seg * SPAN;
  const int E0 = NB + SPAN + 32;      // er[x] = e[E0-x]*1024
  const int chan = b * RES + r;

  // ---- staging B: filter table copy (unrolled) ----
  {
    const uint4* fg = (const uint4*)(fgl + r * FGL_DW);
    uint4* fc4 = (uint4*)fcb;
#pragma unroll
    for (int k = 0; k < 4; ++k) fc4[tid + 512 * k] = fg[tid + 512 * k];
    if (tid < FGL_DW / 4 - 2048) fc4[2048 + tid] = fg[2048 + tid];
  }

  // ---- staging A: fused energy, branchless, unrolled ----
  {
    const float* rp = routed + chan * NF;
    const float* npz = noise + (size_t)chan * NS;
    const int n0base = E0 - 18431;

#define STAGEG(T_)                                                            \
    {                                                                         \
      const int t_ = (T_);                                                    \
      const int n0 = n0base + 8 * t_;                                         \
      const int g = 2303 - t_;                                                \
      const int nc = min(max(n0, 0), NS - 8);                                 \
      const float4 na = *(const float4*)(npz + nc);                           \
      const float4 nb = *(const float4*)(npz + nc + 4);                       \
      float pos0 = fminf(fmaxf(fmaf((float)n0 + 0.5f, 1.f / 256.f, -0.5f), 0.f), 511.f); \
      float pos7 = fminf(fmaxf(fmaf((float)n0 + 7.5f, 1.f / 256.f, -0.5f), 0.f), 511.f); \
      const int ia = min((int)pos0, 510);                                     \
      const int ib = min((int)pos7, 510);                                     \
      const float c0 = rp[ia], c1 = rp[ia + 1];                               \
      const float c2 = rp[ib], c3 = rp[ib + 1];                               \
      const float iaf = (float)ia;                                            \
      const float nv[8] = {na.x, na.y, na.z, na.w, nb.x, nb.y, nb.z, nb.w};   \
      union { _Float16 h[8]; uint4 u; } O;                                    \
      _Pragma("unroll")                                                       \
      for (int k = 0; k < 8; ++k) {                                           \
        const int n = n0 + k;                                                 \
        float pos = fminf(fmaxf(fmaf((float)n + 0.5f, 1.f / 256.f, -0.5f), 0.f), 511.f); \
        float i0f = fminf(floorf(pos), 510.f);                                \
        float fr = pos - i0f;                                                 \
        bool sel = i0f > iaf;                                                 \
        float lo = sel ? c2 : c0;                                             \
        float hi = sel ? c3 : c1;                                             \
        float u = fmaf(fr, hi - lo, lo);                                      \
        float e = (n >= 0 && n < NS) ? u * nv[k] * 1024.f : 0.f;              \
        O.h[7 - k] = (_Float16)e;                                             \
      }                                                                       \
      const int gs = g ^ ((g >> 3) & 7);                                      \
      *(uint4*)(erb + (gs << 4)) = O.u;                                       \
    }

#pragma unroll
    for (int k = 0; k < 4; ++k) STAGEG(tid + 512 * k)
    if (tid < 256) STAGEG(2048 + tid)
#undef STAGEG
  }
  __syncthreads();

  const int w = tid >> 6;
  const int l = tid & 63;
  const int row = l & 31;
  const int h = l >> 5;

  const int gaA = 2048 - 256 * w + 4 * row + h;
  const int gaB = gaA - 128;
  const int qcb = (row & 7) * FC_STRIDE + (row >> 3) + h;

  f32x16 p00, p01, p10, p11;
#pragma unroll
  for (int i = 0; i < 16; ++i) { p00[i] = 0.f; p01[i] = 0.f; p10[i] = 0.f; p11[i] = 0.f; }

#define LOADA(DST, GB, SG_)                                                   \
  { int g = (GB) + 2 * (SG_); int ab = (g ^ ((g >> 3) & 7)) << 4;             \
    DST.u = *(const uint4*)(erb + ab); }
#define LOADBF(DST, SG_, J_)                                                  \
  { int gb = qcb + 2 * (SG_) + 128 * (J_);                                    \
    DST.u = *(const uint4*)(fcb + (gb << 4)); }

  for (int sg = 0; sg < 2; ++sg) {
    Frag B0, A0, A1;
    LOADBF(B0, sg, 0)
    LOADA(A0, gaA, sg) LOADA(A1, gaB, sg)
    p00 = __builtin_amdgcn_mfma_f32_32x32x16_f16(A0.v, B0.v, p00, 0, 0, 0);
    p10 = __builtin_amdgcn_mfma_f32_32x32x16_f16(A1.v, B0.v, p10, 0, 0, 0);
  }
  for (int sg = 2; sg < 66; ++sg) {
    Frag B0, B1, A0, A1;
    LOADBF(B0, sg, 0) LOADBF(B1, sg, 1)
    LOADA(A0, gaA, sg) LOADA(A1, gaB, sg)
    p00 = __builtin_amdgcn_mfma_f32_32x32x16_f16(A0.v, B0.v, p00, 0, 0, 0);
    p01 = __builtin_amdgcn_mfma_f32_32x32x16_f16(A0.v, B1.v, p01, 0, 0, 0);
    p10 = __builtin_amdgcn_mfma_f32_32x32x16_f16(A1.v, B0.v, p10, 0, 0, 0);
    p11 = __builtin_amdgcn_mfma_f32_32x32x16_f16(A1.v, B1.v, p11, 0, 0, 0);
  }

  if (seg == 7 && w == 7) {           // global-top orphan phase-0 half
    f32x16 ax;
#pragma unroll
    for (int i = 0; i < 16; ++i) ax[i] = 0.f;
    const int ge = 4 * row + h;
    for (int sg = 0; sg < 66; ++sg) {
      Frag Bx, Ax;
      LOADBF(Bx, sg, 0)
      LOADA(Ax, ge, sg)
      ax = __builtin_amdgcn_mfma_f32_32x32x16_f16(Ax.v, Bx.v, ax, 0, 0, 0);
    }
#pragma unroll
    for (int i = 0; i < 16; ++i) p11[i] += ax[i];
  }
#undef LOADA
#undef LOADBF

  float* cbase = outp + (size_t)chan * NS;
  const float scale = 1.f / 1024.f;

  {
    float* po = cbase + NB + 1024 * (2 * w + 1);
#pragma unroll
    for (int rg = 0; rg < 16; ++rg) {
      int crow = (rg & 3) + 8 * (rg >> 2) + 4 * h;
      po[row - 32 * crow] = (p10[rg] + p01[rg]) * scale;
    }
  }

  __syncthreads();
  float* scr = (float*)smem;
#pragma unroll
  for (int rg = 0; rg < 16; ++rg) scr[w * 1024 + rg * 64 + l] = p11[rg];
  __syncthreads();

  if (w >= 1) {
    float* po = cbase + NB + 1024 * (2 * w);
#pragma unroll
    for (int rg = 0; rg < 16; ++rg) {
      int crow = (rg & 3) + 8 * (rg >> 2) + 4 * h;
      po[row - 32 * crow] = (p00[rg] + scr[(w - 1) * 1024 + rg * 64 + l]) * scale;
    }
  } else {
#pragma unroll
    for (int rg = 0; rg < 16; ++rg) {
      int crow = (rg & 3) + 8 * (rg >> 2) + 4 * h;
      int y = NB + row - 32 * crow;
      if (y >= 0) atomicAdd(cbase + y, p00[rg] * scale);
    }
  }
  if (w == 7) {
#pragma unroll
    for (int rg = 0; rg < 16; ++rg) {
      int crow = (rg & 3) + 8 * (rg >> 2) + 4 * h;
      int y = NB + SPAN + row - 32 * crow;
      if (y < NS) atomicAdd(cbase + y, p11[rg] * scale);
    }
  }
}

// ---------------------------------------------------------------------------
extern "C" void kernel_launch(void* const* d_in, const int* in_sizes, int n_in,
                              void* d_out, int out_size, void* d_ws, size_t ws_size,
                              hipStream_t stream) {
  const float* forces     = (const float*)d_in[0];
  const float* dmod       = (const float*)d_in[1];
  const float* noise      = (const float*)d_in[2];
  const float* dparam     = (const float*)d_in[3];
  const float* routing    = (const float*)d_in[4];
  const float* W1         = (const float*)d_in[5];
  const float* b1         = (const float*)d_in[6];
  const float* W2         = (const float*)d_in[7];
  const float* b2         = (const float*)d_in[8];
  const float* filters    = (const float*)d_in[9];
  const float* to_control = (const float*)d_in[10];

  float* out = (float*)d_out;
  float* to_ctrl = out;                                  // (B,CPD,NF)
  float* reso = out + BATCH * CPD * NF;                  // (B,RES,NS)

  char* ws = (char*)d_ws;
  float* damped_t = (float*)ws;                          // 512 KB
  float* routed = (float*)(ws + (512 << 10));            // 512 KB
  unsigned* fgl = (unsigned*)(ws + (1 << 20));           // 2.19 MB

  k_scan<<<BATCH, 256, 0, stream>>>(forces, dmod, dparam, damped_t);
  k_hyper<<<BATCH * NF / 4, 256, 0, stream>>>(damped_t, routing, W1, b1, W2, b2,
                                              to_control, routed, to_ctrl);
  k_filter<<<RES, 256, 0, stream>>>(filters, fgl);
  k_zero<<<BATCH * RES, 256, 0, stream>>>(reso);
  k_conv<<<BATCH * RES * (NS / SPAN), 512, 0, stream>>>(routed, noise, reso, fgl);
}